// Round 1
// baseline (95.399 us; speedup 1.0000x reference)
//
#include <hip/hip_runtime.h>
#include <hip/hip_bf16.h>

// Problem constants (B, N1, N2, D) = (256, 32, 32, 512)
#define BB 256
#define NN 32
#define DD 512

// Kernel 1: u[b][d] = sum_n ner[b][n][d];  vT[d][c] = sum_f face[c][f][d]
// One thread per float4 output group. First half of grid -> ner, second -> face.
__global__ __launch_bounds__(256) void reduce_sums(
    const float* __restrict__ ner, const float* __restrict__ face,
    float* __restrict__ u, float* __restrict__ vT) {
  int idx = blockIdx.x * 256 + threadIdx.x;
  const int half = BB * DD / 4;  // 32768 float4 outputs per tensor
  bool is_ner = idx < half;
  int j = is_ner ? idx : idx - half;
  int row = j >> 7;        // DD/4 = 128 float4 per row
  int d4  = j & 127;
  const float* src = is_ner ? ner : face;
  const float4* p = (const float4*)(src + (size_t)row * NN * DD) + d4;
  float4 s = make_float4(0.f, 0.f, 0.f, 0.f);
#pragma unroll
  for (int n = 0; n < NN; ++n) {
    float4 x = p[n * (DD / 4)];
    s.x += x.x; s.y += x.y; s.z += x.z; s.w += x.w;
  }
  if (is_ner) {
    ((float4*)(u + (size_t)row * DD))[d4] = s;
  } else {
    int d = d4 * 4;
    vT[(size_t)(d + 0) * BB + row] = s.x;
    vT[(size_t)(d + 1) * BB + row] = s.y;
    vT[(size_t)(d + 2) * BB + row] = s.z;
    vT[(size_t)(d + 3) * BB + row] = s.w;
  }
}

// Kernel 2: block b computes logits[b][t] = u[b]·v[t] / (N1*N2) for all t,
// then row logsumexp; writes r[b] = logits[b][b] - lse(logits[b][:]).
__global__ __launch_bounds__(256) void row_lse(
    const float* __restrict__ u, const float* __restrict__ vT,
    float* __restrict__ r) {
  int b = blockIdx.x;
  int t = threadIdx.x;
  __shared__ float us[DD];
  __shared__ float red[BB];
  __shared__ float diag_s;

  us[t]       = u[(size_t)b * DD + t];
  us[t + 256] = u[(size_t)b * DD + 256 + t];
  __syncthreads();

  float acc = 0.f;
#pragma unroll 8
  for (int d = 0; d < DD; ++d) {
    acc = fmaf(us[d], vT[(size_t)d * BB + t], acc);  // coalesced across lanes
  }
  float logit = acc * (1.f / (NN * NN));

  if (t == b) diag_s = logit;
  red[t] = logit;
  __syncthreads();
  for (int s = 128; s > 0; s >>= 1) {
    if (t < s) red[t] = fmaxf(red[t], red[t + s]);
    __syncthreads();
  }
  float mx = red[0];
  __syncthreads();
  red[t] = expf(logit - mx);
  __syncthreads();
  for (int s = 128; s > 0; s >>= 1) {
    if (t < s) red[t] += red[t + s];
    __syncthreads();
  }
  if (t == 0) {
    float lse = mx + logf(red[0]);
    r[b] = diag_s - lse;
  }
}

// Kernel 3: out = -mean(r)
__global__ __launch_bounds__(256) void final_reduce(
    const float* __restrict__ r, float* __restrict__ out) {
  int t = threadIdx.x;
  __shared__ float red[BB];
  red[t] = r[t];
  __syncthreads();
  for (int s = 128; s > 0; s >>= 1) {
    if (t < s) red[t] += red[t + s];
    __syncthreads();
  }
  if (t == 0) out[0] = -red[0] * (1.f / BB);
}

extern "C" void kernel_launch(void* const* d_in, const int* in_sizes, int n_in,
                              void* d_out, int out_size, void* d_ws, size_t ws_size,
                              hipStream_t stream) {
  // setup_inputs dict order: face_j first, ner_j second
  const float* face = (const float*)d_in[0];  // (B, N2, D)
  const float* ner  = (const float*)d_in[1];  // (B, N1, D)
  float* u  = (float*)d_ws;          // B*D floats   (512 KB)
  float* vT = u + (size_t)BB * DD;   // D*B floats   (512 KB)
  float* r  = vT + (size_t)DD * BB;  // B floats     (1 KB)

  const int total_threads = 2 * BB * DD / 4;  // 65536
  reduce_sums<<<total_threads / 256, 256, 0, stream>>>(ner, face, u, vT);
  row_lse<<<BB, 256, 0, stream>>>(u, vT, r);
  final_reduce<<<1, 256, 0, stream>>>(r, (float*)d_out);
}